// Round 6
// baseline (283.974 us; speedup 1.0000x reference)
//
#include <hip/hip_runtime.h>

// B=8, S=1024, D=1024, H=16, P=64. FP32 I/O, bf16 MFMA compute.
// convert W+acts -> bf16 (one kernel) | m97-style QKV GEMM (128x128) |
// MFMA batch-softmax attention | final GEMM + sigmoid (64x128, 4 blk/CU).

using short8   = __attribute__((ext_vector_type(8))) short;    // 8 bf16
using floatx4  = __attribute__((ext_vector_type(4))) float;    // MFMA acc 16x16
using floatx16 = __attribute__((ext_vector_type(16))) float;   // MFMA acc 32x32

__device__ __forceinline__ float bf2f(unsigned short u) {
    return __uint_as_float(((unsigned)u) << 16);
}
__device__ __forceinline__ unsigned short f2bf(float f) {   // RNE
    unsigned u = __float_as_uint(f);
    u += 0x7fffu + ((u >> 16) & 1u);
    return (unsigned short)(u >> 16);
}
// two fp32 -> packed bf16 pair (truncation) in one v_perm: lo16=f0, hi16=f1
__device__ __forceinline__ unsigned pack_trunc(float f0, float f1) {
    return __builtin_amdgcn_perm(__float_as_uint(f1), __float_as_uint(f0), 0x07060302u);
}
__device__ __forceinline__ void async_ld16(const void* g, void* l) {
    __builtin_amdgcn_global_load_lds(
        (const __attribute__((address_space(1))) unsigned int*)g,
        (__attribute__((address_space(3))) unsigned int*)l, 16, 0, 0);
}

// ---------------------------------------------------------------------------
// fp32 -> bf16 (RNE): all 7 tensors in one dispatch, contiguous dst.
// Layout: [Wq|Wk|Wv|Wo] (4 x 1M) then [qbf|kbf|vbf] (3 x 8M).
// Fallback path launches only the weight region (first 2048 blocks).
// ---------------------------------------------------------------------------
__global__ __launch_bounds__(256) void convert_all(
    const float* __restrict__ w0, const float* __restrict__ w1,
    const float* __restrict__ w2, const float* __restrict__ w3,
    const float* __restrict__ a0, const float* __restrict__ a1,
    const float* __restrict__ a2, unsigned short* __restrict__ dst)
{
    const size_t WN = (size_t)1024 * 1024;
    const size_t MN = (size_t)8192 * 1024;
    const size_t i = ((size_t)blockIdx.x * 256 + threadIdx.x) * 8;
    const float* src; size_t off;
    if (i < 4 * WN) {
        const float* ws[4] = {w0, w1, w2, w3};
        src = ws[i >> 20]; off = i & (WN - 1);
    } else {
        const size_t r = i - 4 * WN;
        const float* as[3] = {a0, a1, a2};
        src = as[r >> 23]; off = r & (MN - 1);
    }
    float4 a = *(const float4*)(src + off);
    float4 b = *(const float4*)(src + off + 4);
    uint4 o;
    o.x = ((unsigned)f2bf(a.y) << 16) | f2bf(a.x);
    o.y = ((unsigned)f2bf(a.w) << 16) | f2bf(a.z);
    o.z = ((unsigned)f2bf(b.y) << 16) | f2bf(b.x);
    o.w = ((unsigned)f2bf(b.w) << 16) | f2bf(b.z);
    *(uint4*)(dst + i) = o;
}

// ---------------------------------------------------------------------------
// Tiled GEMM (m97 structure): C = A.W^T + bias. BK=32, 4 waves.
// TM64=false: 128x128 tile (2x2 waves of 64x64). TM64=true: 64x128 tile
// (2x2 waves of 32x64) -> 2x blocks for occupancy on small dispatches.
// bf16 LDS k-chunk swizzle: slot = quad ^ ((row>>1)&3) -> each 8-lane b128
// phase hits 8 distinct bank-quads (conflict-free).
// grid.z picks among 3 problem tuples (QKV fusion).
// ---------------------------------------------------------------------------
template<bool AF32, bool SIG, bool TM64>
__global__ __launch_bounds__(256) void gemm128(
    const void* __restrict__ A0, const void* __restrict__ A1, const void* __restrict__ A2,
    const unsigned short* __restrict__ W0, const unsigned short* __restrict__ W1,
    const unsigned short* __restrict__ W2,
    const float* __restrict__ b0, const float* __restrict__ b1, const float* __restrict__ b2,
    void* __restrict__ C0, void* __restrict__ C1, void* __restrict__ C2)
{
    const int z = blockIdx.z;
    const void* Ap = (z == 0) ? A0 : (z == 1) ? A1 : A2;
    const unsigned short* W = (z == 0) ? W0 : (z == 1) ? W1 : W2;
    const float* bias = (z == 0) ? b0 : (z == 1) ? b1 : b2;
    void* Cp = (z == 0) ? C0 : (z == 1) ? C1 : C2;

    constexpr int Kd = 1024, Nd = 1024;
    constexpr int TM = TM64 ? 64 : 128;
    constexpr int MT = TM64 ? 2 : 4;       // 16-row m-tiles per wave
    const int t = threadIdx.x;
    const int w = t >> 6, lane = t & 63;
    const int l15 = lane & 15, quad = lane >> 4;
    const int blockM = blockIdx.x * TM;
    const int blockN = blockIdx.y * 128;
    const int wy = w >> 1, wx = w & 1;

    __shared__ unsigned short Bs[128 * 32];                    // 8 KB
    __shared__ __align__(16) unsigned char AsRaw[TM * 32 * (AF32 ? 4 : 2)];
    float* AsF = (float*)AsRaw;
    unsigned short* AsB = (unsigned short*)AsRaw;

    // bf16 staging: lane covers local row l>>2, slot l&3, stages global
    // chunk g = (l&3) ^ ((l>>3)&3)  [key = (localrow>>1)&3]
    const int br = lane >> 2;
    const int bg = (lane & 3) ^ ((lane >> 3) & 3);
    const unsigned short* Bsrc0 = W + (size_t)(blockN + w * 32 + br) * Kd + bg * 8;
    const unsigned short* Bsrc1 = Bsrc0 + (size_t)16 * Kd;
    unsigned short* Bdst0 = &Bs[(w * 2 + 0) * 512];
    unsigned short* Bdst1 = &Bs[(w * 2 + 1) * 512];

    const float* AsrcF[4]; float* AdstF[4];
    const unsigned short* AsrcB0 = nullptr; const unsigned short* AsrcB1 = nullptr;
    unsigned short* AdstB0 = nullptr; unsigned short* AdstB1 = nullptr;
    if constexpr (AF32) {
        const int ar = lane >> 3;
        const int ag = (lane & 7) ^ (ar & 7);
        #pragma unroll
        for (int j = 0; j < 4; ++j) {
            AsrcF[j] = (const float*)Ap + (size_t)(blockM + w * 32 + j * 8 + ar) * Kd + ag * 4;
            AdstF[j] = AsF + (w * 4 + j) * 256;
        }
    } else if constexpr (TM64) {
        AsrcB0 = (const unsigned short*)Ap + (size_t)(blockM + w * 16 + br) * Kd + bg * 8;
        AdstB0 = &AsB[w * 512];
    } else {
        AsrcB0 = (const unsigned short*)Ap + (size_t)(blockM + w * 32 + br) * Kd + bg * 8;
        AsrcB1 = AsrcB0 + (size_t)16 * Kd;
        AdstB0 = &AsB[(w * 2 + 0) * 512];
        AdstB1 = &AsB[(w * 2 + 1) * 512];
    }

    floatx4 acc[MT][4] = {};

    for (int k0 = 0; k0 < Kd; k0 += 32) {
        if constexpr (AF32) {
            #pragma unroll
            for (int j = 0; j < 4; ++j) async_ld16(AsrcF[j] + k0, AdstF[j]);
        } else if constexpr (TM64) {
            async_ld16(AsrcB0 + k0, AdstB0);
        } else {
            async_ld16(AsrcB0 + k0, AdstB0);
            async_ld16(AsrcB1 + k0, AdstB1);
        }
        async_ld16(Bsrc0 + k0, Bdst0);
        async_ld16(Bsrc1 + k0, Bdst1);
        __syncthreads();

        const int rslot = quad ^ ((l15 >> 1) & 3);
        short8 af[MT], bfr[4];
        #pragma unroll
        for (int mt = 0; mt < MT; ++mt) {
            const int row = wy * (TM / 2) + mt * 16 + l15;
            if constexpr (AF32) {
                const int r7 = l15 & 7;
                const float* ap = AsF + row * 32;
                float4 lo = *(const float4*)(ap + (((quad * 2 + 0) ^ r7) * 4));
                float4 hi = *(const float4*)(ap + (((quad * 2 + 1) ^ r7) * 4));
                union { unsigned u[4]; short8 s; } cv;
                cv.u[0] = pack_trunc(lo.x, lo.y);
                cv.u[1] = pack_trunc(lo.z, lo.w);
                cv.u[2] = pack_trunc(hi.x, hi.y);
                cv.u[3] = pack_trunc(hi.z, hi.w);
                af[mt] = cv.s;
            } else {
                af[mt] = *(const short8*)&AsB[row * 32 + rslot * 8];
            }
        }
        #pragma unroll
        for (int nt = 0; nt < 4; ++nt) {
            const int row = wx * 64 + nt * 16 + l15;
            bfr[nt] = *(const short8*)&Bs[row * 32 + rslot * 8];
        }
        #pragma unroll
        for (int mt = 0; mt < MT; ++mt)
            #pragma unroll
            for (int nt = 0; nt < 4; ++nt)
                acc[mt][nt] = __builtin_amdgcn_mfma_f32_16x16x32_bf16(af[mt], bfr[nt], acc[mt][nt], 0, 0, 0);
        __syncthreads();
    }

    // epilogue: C/D layout col=l15, row=quad*4+r
    #pragma unroll
    for (int nt = 0; nt < 4; ++nt) {
        const int col = blockN + wx * 64 + nt * 16 + l15;
        const float bv = bias[col];
        #pragma unroll
        for (int mt = 0; mt < MT; ++mt) {
            const int row = blockM + wy * (TM / 2) + mt * 16 + quad * 4;
            #pragma unroll
            for (int r = 0; r < 4; ++r) {
                float v = acc[mt][nt][r] + bv;
                if (SIG) {
                    v = 1.0f / (1.0f + __expf(-v));
                    ((float*)Cp)[(size_t)(row + r) * Nd + col] = v;
                } else {
                    ((unsigned short*)Cp)[(size_t)(row + r) * Nd + col] = f2bf(v);
                }
            }
        }
    }
}

// ---------------------------------------------------------------------------
// MFMA attention. grid = (S=1024, 2 p-halves), block = 512 (wave = b).
// Stages (LDS, shorts; total 27648 = 55.3 KB):
//   Vt [8][16][72] @0      : V^T (h-major, q-contig) for PV B-frags
//   Kl [8][64][16] @9216   : K (q-major, h-contig) for score A-frags
//   Ql [8][32][16] @17408  : Q half (p-major, h-contig) for score B-frags
//   Sexp[8][32][72] @9216  : exp(scores) [p][q], overlays Kl+Ql after scores
//   Ol [8][16][36] @9216+b*2304 : out [h][p], overlays own Sexp plane
// Den stage thread map (p=t>>4, q0=(t&15)*4): 16-lane phases sweep 32
// consecutive dwords -> conflict-free b64 (was 4-way with p=t&31).
// ---------------------------------------------------------------------------
__global__ __launch_bounds__(512) void attn_mfma(
    const unsigned short* __restrict__ Q,
    const unsigned short* __restrict__ Kt,
    const unsigned short* __restrict__ Vt,
    unsigned short* __restrict__ O2)
{
    constexpr int VOFF = 0;        // shorts
    constexpr int UOFF = 9216;     // shorts (16B-aligned: 18432 B)
    constexpr int QOFF = UOFF + 8192;
    __shared__ __align__(16) unsigned short lds[UOFF + 18432];

    const int s  = blockIdx.x;
    const int ph = blockIdx.y;
    const int t  = threadIdx.x;
    const int w  = t >> 6;          // wave = b
    const int l  = t & 63;
    const int l15 = l & 15, l31 = l & 31, half = l >> 5, quad = l >> 4;

    const size_t gb = ((size_t)w * 1024 + s) * 1024;  // shorts

    // ---- load phase ----
    {
        const unsigned* vg = (const unsigned*)(Vt + gb);
        unsigned* vd = (unsigned*)lds;
        #pragma unroll
        for (int it = 0; it < 8; ++it) {
            const int h = it * 2 + half;
            vd[w * 576 + h * 36 + l31] = vg[h * 32 + l31];
        }
        const unsigned short* kg = Kt + gb;
        unsigned* kd = (unsigned*)(lds + UOFF);
        #pragma unroll
        for (int h2 = 0; h2 < 8; ++h2) {
            unsigned klo = kg[(2 * h2) * 64 + l];
            unsigned khi = kg[(2 * h2 + 1) * 64 + l];
            kd[w * 512 + l * 8 + h2] = klo | (khi << 16);
        }
        const unsigned short* qg = Q + gb + ph * 32;
        unsigned* qd = (unsigned*)(lds + QOFF);
        #pragma unroll
        for (int it = 0; it < 4; ++it) {
            const int h = it * 4 + half * 2;
            unsigned qlo = qg[h * 64 + l31];
            unsigned qhi = qg[(h + 1) * 64 + l31];
            qd[w * 256 + l31 * 8 + it * 2 + half] = qlo | (qhi << 16);
        }
    }
    __syncthreads();

    // ---- scores: A=K (m=q), B=Q (n=p), K=16=h ----
    floatx16 sc[2];
    {
        short8 qf = *(const short8*)&lds[QOFF + w * 512 + l31 * 16 + half * 8];
        short8 kf0 = *(const short8*)&lds[UOFF + w * 1024 + l31 * 16 + half * 8];
        short8 kf1 = *(const short8*)&lds[UOFF + w * 1024 + (32 + l31) * 16 + half * 8];
        floatx16 z = {};
        sc[0] = __builtin_amdgcn_mfma_f32_32x32x16_bf16(kf0, qf, z, 0, 0, 0);
        sc[1] = __builtin_amdgcn_mfma_f32_32x32x16_bf16(kf1, qf, z, 0, 0, 0);
    }
    __syncthreads();   // K/Q region dead -> reuse as Sexp

    // ---- exp + Sexp[p][q] writes (p = l31, q from C layout) ----
    {
        unsigned short* sx = lds + UOFF + w * 2304 + l31 * 72;
        #pragma unroll
        for (int nt = 0; nt < 2; ++nt) {
            #pragma unroll
            for (int rg = 0; rg < 4; ++rg) {
                float e0 = __expf(sc[nt][4 * rg + 0] * 0.125f);
                float e1 = __expf(sc[nt][4 * rg + 1] * 0.125f);
                float e2 = __expf(sc[nt][4 * rg + 2] * 0.125f);
                float e3 = __expf(sc[nt][4 * rg + 3] * 0.125f);
                uint2 pk = { pack_trunc(e0, e1), pack_trunc(e2, e3) };
                const int q0 = nt * 32 + rg * 8 + half * 4;
                *(uint2*)&sx[q0] = pk;
            }
        }
    }
    __syncthreads();

    // ---- batch-softmax denominators: thread owns (p=t>>4, q0=(t&15)*4) ----
    {
        const int p  = t >> 4;
        const int q0 = (t & 15) * 4;
        unsigned short* base = lds + UOFF + p * 72 + q0;
        float fv[8][4];
        float den0 = 0.f, den1 = 0.f, den2 = 0.f, den3 = 0.f;
        #pragma unroll
        for (int b = 0; b < 8; ++b) {
            uint2 v = *(const uint2*)&base[b * 2304];
            fv[b][0] = bf2f((unsigned short)(v.x & 0xffff));
            fv[b][1] = bf2f((unsigned short)(v.x >> 16));
            fv[b][2] = bf2f((unsigned short)(v.y & 0xffff));
            fv[b][3] = bf2f((unsigned short)(v.y >> 16));
            den0 += fv[b][0]; den1 += fv[b][1]; den2 += fv[b][2]; den3 += fv[b][3];
        }
        const float r0 = __builtin_amdgcn_rcpf(den0);
        const float r1 = __builtin_amdgcn_rcpf(den1);
        const float r2 = __builtin_amdgcn_rcpf(den2);
        const float r3 = __builtin_amdgcn_rcpf(den3);
        #pragma unroll
        for (int b = 0; b < 8; ++b) {
            uint2 pk = { pack_trunc(fv[b][0] * r0, fv[b][1] * r1),
                         pack_trunc(fv[b][2] * r2, fv[b][3] * r3) };
            *(uint2*)&base[b * 2304] = pk;
        }
    }
    __syncthreads();

    // ---- PV: A=weights[p][q], B=Vt[h][q]; out[p][h] ----
    floatx4 o[2] = {};
    #pragma unroll
    for (int qc = 0; qc < 2; ++qc) {
        short8 vf = *(const short8*)&lds[VOFF + w * 1152 + l15 * 72 + qc * 32 + quad * 8];
        #pragma unroll
        for (int mt = 0; mt < 2; ++mt) {
            short8 wf = *(const short8*)&lds[UOFF + w * 2304 + (mt * 16 + l15) * 72 + qc * 32 + quad * 8];
            o[mt] = __builtin_amdgcn_mfma_f32_16x16x32_bf16(wf, vf, o[mt], 0, 0, 0);
        }
    }
    {
        unsigned short* ol = lds + UOFF + w * 2304 + l15 * 36;
        #pragma unroll
        for (int mt = 0; mt < 2; ++mt) {
            uint2 pk = { pack_trunc(o[mt][0], o[mt][1]), pack_trunc(o[mt][2], o[mt][3]) };
            *(uint2*)&ol[mt * 16 + quad * 4] = pk;
        }
    }
    __syncthreads();

    // ---- coalesced store: per wave (b), 256 dwords ----
    {
        unsigned* outdw = (unsigned*)O2;
        const unsigned* ol = (const unsigned*)(lds + UOFF + w * 2304);
        const size_t gdw = ((size_t)w * 1024 + s) * 512 + ph * 16;
        #pragma unroll
        for (int i = 0; i < 4; ++i) {
            const int d = i * 64 + l;
            const int h = d >> 4, pq = d & 15;
            outdw[gdw + h * 32 + pq] = ol[h * 18 + pq];
        }
    }
}

// ---------------------------------------------------------------------------
extern "C" void kernel_launch(void* const* d_in, const int* in_sizes, int n_in,
                              void* d_out, int out_size, void* d_ws, size_t ws_size,
                              hipStream_t stream) {
    const float* query = (const float*)d_in[0];
    const float* key_  = (const float*)d_in[1];
    const float* value = (const float*)d_in[2];
    const float* Wq = (const float*)d_in[3];
    const float* bq = (const float*)d_in[4];
    const float* Wk = (const float*)d_in[5];
    const float* bk = (const float*)d_in[6];
    const float* Wv = (const float*)d_in[7];
    const float* bv = (const float*)d_in[8];
    const float* Wo = (const float*)d_in[9];
    const float* bo = (const float*)d_in[10];

    const size_t WN = (size_t)1024 * 1024;
    const size_t MN = (size_t)8192 * 1024;

    unsigned short* Wbf = (unsigned short*)d_ws;
    unsigned short* Wq_bf = Wbf;
    unsigned short* Wk_bf = Wbf + WN;
    unsigned short* Wv_bf = Wbf + 2 * WN;
    unsigned short* Wo_bf = Wbf + 3 * WN;

    const bool big = ws_size >= (4 * WN + 6 * MN) * sizeof(unsigned short); // 104 MB

    unsigned short* Qb; unsigned short* Kb; unsigned short* Vb;
    if (big) {
        unsigned short* abf = Wbf + 4 * WN;
        Qb = abf + 3 * MN; Kb = Qb + MN; Vb = Kb + MN;
        // weights + activations in one dispatch (contiguous dst)
        convert_all<<<dim3(14336), dim3(256), 0, stream>>>(
            Wq, Wk, Wv, Wo, query, key_, value, Wbf);
        gemm128<false, false, false><<<dim3(64, 8, 3), dim3(256), 0, stream>>>(
            abf, abf + MN, abf + 2 * MN, Wq_bf, Wk_bf, Wv_bf, bq, bk, bv, Qb, Kb, Vb);
    } else {
        Qb = Wbf + 4 * WN; Kb = Qb + MN; Vb = Kb + MN;
        convert_all<<<dim3(2048), dim3(256), 0, stream>>>(
            Wq, Wk, Wv, Wo, query, key_, value, Wbf);   // weights only
        gemm128<true, false, false><<<dim3(64, 8, 3), dim3(256), 0, stream>>>(
            query, key_, value, Wq_bf, Wk_bf, Wv_bf, bq, bk, bv, Qb, Kb, Vb);
    }

    unsigned short* O2 = Qb;   // alias (safe, see attn_mfma)
    attn_mfma<<<dim3(1024, 2), dim3(512), 0, stream>>>(Qb, Kb, Vb, O2);

    // 64x128 tiles -> 1024 blocks = 4/CU for the small final GEMM
    gemm128<false, true, true><<<dim3(128, 8, 1), dim3(256), 0, stream>>>(
        O2, O2, O2, Wo_bf, Wo_bf, Wo_bf, bo, bo, bo, d_out, d_out, d_out);
}